// Round 1
// baseline (467.210 us; speedup 1.0000x reference)
//
#include <hip/hip_runtime.h>

// pre[i] = dot(user_emb[user[i],:], item_emb[:,item[i]]); out = relu(4-relu(4-pre))+1
// Strategy: transpose item_emb (K=64 x N) -> itemT (N x 64) in d_ws so both
// gathers are 256B-contiguous rows, then a coalesced 16-lanes-per-output
// gather+dot kernel.

#define KDIM 64

__global__ void itemT_transpose_kernel(const float* __restrict__ item_emb,
                                       float* __restrict__ itemT, int N) {
    // One block transposes a 64(K) x 64(n) tile.
    __shared__ float tile[64][65];   // +1 pad: conflict-free column reads
    const int n0 = blockIdx.x * 64;
    const int t  = threadIdx.x;      // 256 threads

    // Load: lane group reads 64 consecutive floats of row k (coalesced 256B).
    {
        const int c  = t & 63;
        const int kq = t >> 6;       // 0..3
        #pragma unroll
        for (int kk = 0; kk < 16; ++kk) {
            const int k = kk * 4 + kq;
            const int n = n0 + c;
            if (n < N) tile[k][c] = item_emb[(size_t)k * N + n];
        }
    }
    __syncthreads();
    // Store: 64 lanes write one itemT row (256B contiguous). LDS read
    // tile[k][c], k varies per lane -> stride 65 -> 2-way alias only (free).
    {
        const int k  = t & 63;
        const int cq = t >> 6;       // 0..3
        #pragma unroll
        for (int cc = 0; cc < 16; ++cc) {
            const int c = cc * 4 + cq;
            const int n = n0 + c;
            if (n < N) itemT[(size_t)n * KDIM + k] = tile[k][c];
        }
    }
}

__device__ __forceinline__ float finish(float s) {
    float y = fmaxf(4.0f - s, 0.0f);
    return fmaxf(4.0f - y, 0.0f) + 1.0f;
}

// 16 lanes per output: lane l loads float4 #l of the 64-float user row and
// itemT row (16 x 16B = 256B contiguous per quarter-wave), then shfl reduce.
__global__ void gather_dot_kernel(const int* __restrict__ user,
                                  const int* __restrict__ item,
                                  const float* __restrict__ user_emb,
                                  const float* __restrict__ itemT,
                                  float* __restrict__ out, int B) {
    const int t = threadIdx.x;
    const int l = t & 15;
    const int i = blockIdx.x * 16 + (t >> 4);
    if (i >= B) return;

    const int u  = user[i];
    const int it = item[i];

    const float4* up = reinterpret_cast<const float4*>(user_emb) + (size_t)u * 16;
    const float4* vp = reinterpret_cast<const float4*>(itemT)    + (size_t)it * 16;
    const float4 a = up[l];
    const float4 b = vp[l];
    float s = a.x * b.x + a.y * b.y + a.z * b.z + a.w * b.w;

    s += __shfl_xor(s, 1);
    s += __shfl_xor(s, 2);
    s += __shfl_xor(s, 4);
    s += __shfl_xor(s, 8);

    if (l == 0) out[i] = finish(s);
}

// Fallback if d_ws can't hold itemT (N*64*4 = 128 MB): direct strided column
// reads. Slow but correct.
__global__ void gather_dot_direct(const int* __restrict__ user,
                                  const int* __restrict__ item,
                                  const float* __restrict__ user_emb,
                                  const float* __restrict__ item_emb,
                                  float* __restrict__ out, int B, int N) {
    const int i = blockIdx.x * blockDim.x + threadIdx.x;
    if (i >= B) return;
    const int u  = user[i];
    const int it = item[i];
    const float* ur = user_emb + (size_t)u * KDIM;
    float s = 0.0f;
    #pragma unroll
    for (int k = 0; k < KDIM; ++k)
        s += ur[k] * item_emb[(size_t)k * N + it];
    out[i] = finish(s);
}

extern "C" void kernel_launch(void* const* d_in, const int* in_sizes, int n_in,
                              void* d_out, int out_size, void* d_ws, size_t ws_size,
                              hipStream_t stream) {
    const int*   user     = (const int*)d_in[0];
    const int*   item     = (const int*)d_in[1];
    const float* user_emb = (const float*)d_in[2];
    const float* item_emb = (const float*)d_in[3];
    float*       out      = (float*)d_out;

    const int B = in_sizes[0];
    const int N = in_sizes[3] / KDIM;   // item_emb is (K, N)

    const size_t need = (size_t)N * KDIM * sizeof(float);
    if (ws_size >= need) {
        float* itemT = (float*)d_ws;
        const int ntiles = (N + 63) / 64;
        itemT_transpose_kernel<<<ntiles, 256, 0, stream>>>(item_emb, itemT, N);
        gather_dot_kernel<<<(B + 15) / 16, 256, 0, stream>>>(user, item, user_emb,
                                                             itemT, out, B);
    } else {
        gather_dot_direct<<<(B + 255) / 256, 256, 0, stream>>>(user, item, user_emb,
                                                               item_emb, out, B, N);
    }
}

// Round 2
// 466.059 us; speedup vs baseline: 1.0025x; 1.0025x over previous
//
#include <hip/hip_runtime.h>

// pre[i] = dot(user_emb[user[i],:], item_emb[:,item[i]]); out = relu(4-relu(4-pre))+1
// Stage 1: transpose item_emb (K=64 x N) -> itemT (N x 64) in d_ws, float4 on
//          BOTH global sides (16B/lane), LDS scalar redistribution with +1 pad.
// Stage 2: gather+dot, 16 lanes per output, 256B-coalesced row loads.

#define KDIM 64

__global__ void itemT_transpose_kernel(const float* __restrict__ item_emb,
                                       float* __restrict__ itemT, int N) {
    // One block transposes a 64(K) x 64(n) tile. 256 threads.
    __shared__ float tile[64][65];   // 65*x mod 32 == x mod 32 -> column reads 2-way only (free)
    const int n0 = blockIdx.x * 64;
    const int t  = threadIdx.x;
    const int q  = t & 15;           // float4 group 0..15
    const int c4 = q * 4;            // column offset within tile
    const int k0 = t >> 4;           // 0..15
    const bool full = (n0 + 64 <= N);

    // Phase 1: global float4 read of item_emb rows -> LDS (as-is layout).
    if (full) {
        #pragma unroll
        for (int p = 0; p < 4; ++p) {
            const int k = k0 + 16 * p;
            const float4 v = *reinterpret_cast<const float4*>(
                &item_emb[(size_t)k * N + n0 + c4]);
            tile[k][c4 + 0] = v.x; tile[k][c4 + 1] = v.y;
            tile[k][c4 + 2] = v.z; tile[k][c4 + 3] = v.w;
        }
    } else {
        #pragma unroll
        for (int p = 0; p < 4; ++p) {
            const int k = k0 + 16 * p;
            #pragma unroll
            for (int j = 0; j < 4; ++j) {
                const int n = n0 + c4 + j;
                tile[k][c4 + j] = (n < N) ? item_emb[(size_t)k * N + n] : 0.0f;
            }
        }
    }
    __syncthreads();

    // Phase 2: LDS column reads (bank = (4q+j+r) mod 32, 2-way, free) ->
    //          global float4 write of itemT rows (256B contiguous per 16 lanes).
    #pragma unroll
    for (int p = 0; p < 4; ++p) {
        const int r = k0 + 16 * p;       // local item index within tile
        const int n = n0 + r;
        if (!full && n >= N) continue;
        float4 v;
        v.x = tile[c4 + 0][r];
        v.y = tile[c4 + 1][r];
        v.z = tile[c4 + 2][r];
        v.w = tile[c4 + 3][r];
        *reinterpret_cast<float4*>(&itemT[(size_t)n * KDIM + c4]) = v;
    }
}

__device__ __forceinline__ float finish(float s) {
    float y = fmaxf(4.0f - s, 0.0f);
    return fmaxf(4.0f - y, 0.0f) + 1.0f;
}

// 16 lanes per output: lane l loads float4 #l of the 64-float user row and
// itemT row (16 x 16B = 256B contiguous per quarter-wave), then shfl reduce.
__global__ void gather_dot_kernel(const int* __restrict__ user,
                                  const int* __restrict__ item,
                                  const float* __restrict__ user_emb,
                                  const float* __restrict__ itemT,
                                  float* __restrict__ out, int B) {
    const int t = threadIdx.x;
    const int l = t & 15;
    const int i = blockIdx.x * 16 + (t >> 4);
    if (i >= B) return;

    const int u  = user[i];
    const int it = item[i];

    const float4 a = reinterpret_cast<const float4*>(user_emb)[(size_t)u * 16 + l];
    const float4 b = reinterpret_cast<const float4*>(itemT)[(size_t)it * 16 + l];
    float s = a.x * b.x;
    s = fmaf(a.y, b.y, s);
    s = fmaf(a.z, b.z, s);
    s = fmaf(a.w, b.w, s);

    s += __shfl_xor(s, 1);
    s += __shfl_xor(s, 2);
    s += __shfl_xor(s, 4);
    s += __shfl_xor(s, 8);

    if (l == 0) out[i] = finish(s);
}

// Fallback if d_ws can't hold itemT (N*64*4 = 128 MB): direct strided column
// reads. Slow but correct.
__global__ void gather_dot_direct(const int* __restrict__ user,
                                  const int* __restrict__ item,
                                  const float* __restrict__ user_emb,
                                  const float* __restrict__ item_emb,
                                  float* __restrict__ out, int B, int N) {
    const int i = blockIdx.x * blockDim.x + threadIdx.x;
    if (i >= B) return;
    const int u  = user[i];
    const int it = item[i];
    const float* ur = user_emb + (size_t)u * KDIM;
    float s = 0.0f;
    #pragma unroll
    for (int k = 0; k < KDIM; ++k)
        s = fmaf(ur[k], item_emb[(size_t)k * N + it], s);
    out[i] = finish(s);
}

extern "C" void kernel_launch(void* const* d_in, const int* in_sizes, int n_in,
                              void* d_out, int out_size, void* d_ws, size_t ws_size,
                              hipStream_t stream) {
    const int*   user     = (const int*)d_in[0];
    const int*   item     = (const int*)d_in[1];
    const float* user_emb = (const float*)d_in[2];
    const float* item_emb = (const float*)d_in[3];
    float*       out      = (float*)d_out;

    const int B = in_sizes[0];
    const int N = in_sizes[3] / KDIM;   // item_emb is (K, N)

    const size_t need = (size_t)N * KDIM * sizeof(float);
    if (ws_size >= need) {
        float* itemT = (float*)d_ws;
        const int ntiles = (N + 63) / 64;
        itemT_transpose_kernel<<<ntiles, 256, 0, stream>>>(item_emb, itemT, N);
        gather_dot_kernel<<<(B + 15) / 16, 256, 0, stream>>>(user, item, user_emb,
                                                             itemT, out, B);
    } else {
        gather_dot_direct<<<(B + 255) / 256, 256, 0, stream>>>(user, item, user_emb,
                                                               item_emb, out, B, N);
    }
}

// Round 3
// 454.552 us; speedup vs baseline: 1.0278x; 1.0253x over previous
//
#include <hip/hip_runtime.h>

// pre[i] = dot(user_emb[user[i],:], item_emb[:,item[i]]); out = relu(4-relu(4-pre))+1
// Stage 1: transpose item_emb (K=64 x N) -> itemT (N x 64) in d_ws (nontemporal
//          read of item_emb; itemT kept cacheable for stage 2).
// Stage 2: gather+dot. 16 lanes per output, 2 outputs per lane-group (ILP x2),
//          nontemporal user-row loads (use-once) so itemT stays L3-resident.

#define KDIM 64

typedef float f4 __attribute__((ext_vector_type(4)));

__global__ void itemT_transpose_kernel(const float* __restrict__ item_emb,
                                       float* __restrict__ itemT, int N) {
    // One block transposes a 64(K) x 64(n) tile. 256 threads.
    __shared__ float tile[64][65];   // 65*x mod 32 == x mod 32 -> column reads 2-way only (free)
    const int n0 = blockIdx.x * 64;
    const int t  = threadIdx.x;
    const int q  = t & 15;           // float4 group 0..15
    const int c4 = q * 4;            // column offset within tile
    const int k0 = t >> 4;           // 0..15
    const bool full = (n0 + 64 <= N);

    // Phase 1: nontemporal float4 read of item_emb rows -> LDS.
    if (full) {
        #pragma unroll
        for (int p = 0; p < 4; ++p) {
            const int k = k0 + 16 * p;
            const f4 v = __builtin_nontemporal_load(
                reinterpret_cast<const f4*>(&item_emb[(size_t)k * N + n0 + c4]));
            tile[k][c4 + 0] = v[0]; tile[k][c4 + 1] = v[1];
            tile[k][c4 + 2] = v[2]; tile[k][c4 + 3] = v[3];
        }
    } else {
        #pragma unroll
        for (int p = 0; p < 4; ++p) {
            const int k = k0 + 16 * p;
            #pragma unroll
            for (int j = 0; j < 4; ++j) {
                const int n = n0 + c4 + j;
                tile[k][c4 + j] = (n < N) ? item_emb[(size_t)k * N + n] : 0.0f;
            }
        }
    }
    __syncthreads();

    // Phase 2: LDS column reads (2-way alias, free) -> float4 itemT row writes.
    #pragma unroll
    for (int p = 0; p < 4; ++p) {
        const int r = k0 + 16 * p;       // local item index within tile
        const int n = n0 + r;
        if (!full && n >= N) continue;
        f4 v;
        v[0] = tile[c4 + 0][r];
        v[1] = tile[c4 + 1][r];
        v[2] = tile[c4 + 2][r];
        v[3] = tile[c4 + 3][r];
        *reinterpret_cast<f4*>(&itemT[(size_t)n * KDIM + c4]) = v;
    }
}

__device__ __forceinline__ float finish(float s) {
    float y = fmaxf(4.0f - s, 0.0f);
    return fmaxf(4.0f - y, 0.0f) + 1.0f;
}

// 16 lanes per output, 2 outputs per lane-group for ILP. Lane l loads float4
// #l of each 64-float row (16 x 16B = 256B coalesced per quarter-wave).
__global__ void gather_dot_kernel(const int* __restrict__ user,
                                  const int* __restrict__ item,
                                  const float* __restrict__ user_emb,
                                  const float* __restrict__ itemT,
                                  float* __restrict__ out, int B) {
    const int t = threadIdx.x;
    const int l = t & 15;
    const int g = t >> 4;                       // 0..15
    const int i0 = blockIdx.x * 32 + g;
    const int i1 = i0 + 16;
    const bool v0 = (i0 < B);
    const bool v1 = (i1 < B);

    const int u0 = v0 ? user[i0] : 0;
    const int c0 = v0 ? item[i0] : 0;
    const int u1 = v1 ? user[i1] : 0;
    const int c1 = v1 ? item[i1] : 0;

    const f4* UE = reinterpret_cast<const f4*>(user_emb);
    const f4* IT = reinterpret_cast<const f4*>(itemT);

    // 4 independent 256B-coalesced loads in flight per thread.
    const f4 a0 = __builtin_nontemporal_load(UE + (size_t)u0 * 16 + l);
    const f4 a1 = __builtin_nontemporal_load(UE + (size_t)u1 * 16 + l);
    const f4 b0 = IT[(size_t)c0 * 16 + l];
    const f4 b1 = IT[(size_t)c1 * 16 + l];

    float s0 = a0[0] * b0[0];
    float s1 = a1[0] * b1[0];
    s0 = fmaf(a0[1], b0[1], s0);  s1 = fmaf(a1[1], b1[1], s1);
    s0 = fmaf(a0[2], b0[2], s0);  s1 = fmaf(a1[2], b1[2], s1);
    s0 = fmaf(a0[3], b0[3], s0);  s1 = fmaf(a1[3], b1[3], s1);

    #pragma unroll
    for (int d = 1; d < 16; d <<= 1) {
        s0 += __shfl_xor(s0, d);
        s1 += __shfl_xor(s1, d);
    }

    if (l == 0) {
        if (v0) out[i0] = finish(s0);
        if (v1) out[i1] = finish(s1);
    }
}

// Fallback if d_ws can't hold itemT (N*64*4 = 128 MB): direct strided column
// reads. Slow but correct.
__global__ void gather_dot_direct(const int* __restrict__ user,
                                  const int* __restrict__ item,
                                  const float* __restrict__ user_emb,
                                  const float* __restrict__ item_emb,
                                  float* __restrict__ out, int B, int N) {
    const int i = blockIdx.x * blockDim.x + threadIdx.x;
    if (i >= B) return;
    const int u  = user[i];
    const int it = item[i];
    const float* ur = user_emb + (size_t)u * KDIM;
    float s = 0.0f;
    #pragma unroll
    for (int k = 0; k < KDIM; ++k)
        s = fmaf(ur[k], item_emb[(size_t)k * N + it], s);
    out[i] = finish(s);
}

extern "C" void kernel_launch(void* const* d_in, const int* in_sizes, int n_in,
                              void* d_out, int out_size, void* d_ws, size_t ws_size,
                              hipStream_t stream) {
    const int*   user     = (const int*)d_in[0];
    const int*   item     = (const int*)d_in[1];
    const float* user_emb = (const float*)d_in[2];
    const float* item_emb = (const float*)d_in[3];
    float*       out      = (float*)d_out;

    const int B = in_sizes[0];
    const int N = in_sizes[3] / KDIM;   // item_emb is (K, N)

    const size_t need = (size_t)N * KDIM * sizeof(float);
    if (ws_size >= need) {
        float* itemT = (float*)d_ws;
        const int ntiles = (N + 63) / 64;
        itemT_transpose_kernel<<<ntiles, 256, 0, stream>>>(item_emb, itemT, N);
        gather_dot_kernel<<<(B + 31) / 32, 256, 0, stream>>>(user, item, user_emb,
                                                             itemT, out, B);
    } else {
        gather_dot_direct<<<(B + 255) / 256, 256, 0, stream>>>(user, item, user_emb,
                                                               item_emb, out, B, N);
    }
}

// Round 4
// 439.971 us; speedup vs baseline: 1.0619x; 1.0331x over previous
//
#include <hip/hip_runtime.h>

// pre[i] = dot(user_emb[user[i],:], item_emb[:,item[i]]); out = relu(4-relu(4-pre))+1
// Stage 1: transpose+convert item_emb (K=64 x N, fp32) -> itemT (N x 64, fp16)
//          in d_ws. 64 MB result stays L3-resident for stage 2.
// Stage 2: gather+dot. 16 lanes per output, 2 outputs per lane-group.
//          user rows: fp32 256B nontemporal (use-once stream);
//          itemT rows: fp16 128B cached (L3 reuse).

#define KDIM 64

typedef float     f4 __attribute__((ext_vector_type(4)));
typedef _Float16  h4 __attribute__((ext_vector_type(4)));

__global__ void itemT_transpose_kernel(const float* __restrict__ item_emb,
                                       _Float16* __restrict__ itemT, int N) {
    // One block transposes a 64(K) x 64(n) tile. 256 threads.
    __shared__ float tile[64][65];   // 65*x mod 32 == x mod 32 -> column reads 2-way only (free)
    const int n0 = blockIdx.x * 64;
    const int t  = threadIdx.x;
    const int q  = t & 15;           // float4 group 0..15
    const int c4 = q * 4;            // column offset within tile
    const int k0 = t >> 4;           // 0..15
    const bool full = (n0 + 64 <= N);

    // Phase 1: nontemporal float4 read of item_emb rows -> LDS.
    if (full) {
        #pragma unroll
        for (int p = 0; p < 4; ++p) {
            const int k = k0 + 16 * p;
            const f4 v = __builtin_nontemporal_load(
                reinterpret_cast<const f4*>(&item_emb[(size_t)k * N + n0 + c4]));
            tile[k][c4 + 0] = v[0]; tile[k][c4 + 1] = v[1];
            tile[k][c4 + 2] = v[2]; tile[k][c4 + 3] = v[3];
        }
    } else {
        #pragma unroll
        for (int p = 0; p < 4; ++p) {
            const int k = k0 + 16 * p;
            #pragma unroll
            for (int j = 0; j < 4; ++j) {
                const int n = n0 + c4 + j;
                tile[k][c4 + j] = (n < N) ? item_emb[(size_t)k * N + n] : 0.0f;
            }
        }
    }
    __syncthreads();

    // Phase 2: LDS column reads (2-way alias, free) -> fp16 convert ->
    //          8B/lane writes; 16 lanes cover one 128B itemT row.
    #pragma unroll
    for (int p = 0; p < 4; ++p) {
        const int r = k0 + 16 * p;       // local item index within tile
        const int n = n0 + r;
        if (!full && n >= N) continue;
        h4 v;
        v[0] = (_Float16)tile[c4 + 0][r];
        v[1] = (_Float16)tile[c4 + 1][r];
        v[2] = (_Float16)tile[c4 + 2][r];
        v[3] = (_Float16)tile[c4 + 3][r];
        *reinterpret_cast<h4*>(&itemT[(size_t)n * KDIM + c4]) = v;
    }
}

__device__ __forceinline__ float finish(float s) {
    float y = fmaxf(4.0f - s, 0.0f);
    return fmaxf(4.0f - y, 0.0f) + 1.0f;
}

// 16 lanes per output, 2 outputs per lane-group. Lane l: float4 #l of the
// user row (256B coalesced) + h4 #l of the itemT row (128B coalesced).
__global__ void gather_dot_kernel(const int* __restrict__ user,
                                  const int* __restrict__ item,
                                  const float* __restrict__ user_emb,
                                  const _Float16* __restrict__ itemT,
                                  float* __restrict__ out, int B) {
    const int t = threadIdx.x;
    const int l = t & 15;
    const int g = t >> 4;                       // 0..15
    const int i0 = blockIdx.x * 32 + g;
    const int i1 = i0 + 16;
    const bool v0 = (i0 < B);
    const bool v1 = (i1 < B);

    const int u0 = v0 ? user[i0] : 0;
    const int c0 = v0 ? item[i0] : 0;
    const int u1 = v1 ? user[i1] : 0;
    const int c1 = v1 ? item[i1] : 0;

    const f4* UE = reinterpret_cast<const f4*>(user_emb);
    const h4* IT = reinterpret_cast<const h4*>(itemT);

    // Independent coalesced loads in flight: 2x16B user (nontemporal, HBM
    // stream) + 2x8B item (cached, L3-resident 64 MB table).
    const f4 a0 = __builtin_nontemporal_load(UE + (size_t)u0 * 16 + l);
    const f4 a1 = __builtin_nontemporal_load(UE + (size_t)u1 * 16 + l);
    const h4 b0 = IT[(size_t)c0 * 16 + l];
    const h4 b1 = IT[(size_t)c1 * 16 + l];

    float s0 = a0[0] * (float)b0[0];
    float s1 = a1[0] * (float)b1[0];
    s0 = fmaf(a0[1], (float)b0[1], s0);  s1 = fmaf(a1[1], (float)b1[1], s1);
    s0 = fmaf(a0[2], (float)b0[2], s0);  s1 = fmaf(a1[2], (float)b1[2], s1);
    s0 = fmaf(a0[3], (float)b0[3], s0);  s1 = fmaf(a1[3], (float)b1[3], s1);

    #pragma unroll
    for (int d = 1; d < 16; d <<= 1) {
        s0 += __shfl_xor(s0, d);
        s1 += __shfl_xor(s1, d);
    }

    if (l == 0) {
        if (v0) out[i0] = finish(s0);
        if (v1) out[i1] = finish(s1);
    }
}

// Fallback if d_ws can't hold itemT (N*64*2 = 64 MB): direct strided column
// reads. Slow but correct.
__global__ void gather_dot_direct(const int* __restrict__ user,
                                  const int* __restrict__ item,
                                  const float* __restrict__ user_emb,
                                  const float* __restrict__ item_emb,
                                  float* __restrict__ out, int B, int N) {
    const int i = blockIdx.x * blockDim.x + threadIdx.x;
    if (i >= B) return;
    const int u  = user[i];
    const int it = item[i];
    const float* ur = user_emb + (size_t)u * KDIM;
    float s = 0.0f;
    #pragma unroll
    for (int k = 0; k < KDIM; ++k)
        s = fmaf(ur[k], item_emb[(size_t)k * N + it], s);
    out[i] = finish(s);
}

extern "C" void kernel_launch(void* const* d_in, const int* in_sizes, int n_in,
                              void* d_out, int out_size, void* d_ws, size_t ws_size,
                              hipStream_t stream) {
    const int*   user     = (const int*)d_in[0];
    const int*   item     = (const int*)d_in[1];
    const float* user_emb = (const float*)d_in[2];
    const float* item_emb = (const float*)d_in[3];
    float*       out      = (float*)d_out;

    const int B = in_sizes[0];
    const int N = in_sizes[3] / KDIM;   // item_emb is (K, N)

    const size_t need = (size_t)N * KDIM * sizeof(_Float16);
    if (ws_size >= need) {
        _Float16* itemT = (_Float16*)d_ws;
        const int ntiles = (N + 63) / 64;
        itemT_transpose_kernel<<<ntiles, 256, 0, stream>>>(item_emb, itemT, N);
        gather_dot_kernel<<<(B + 31) / 32, 256, 0, stream>>>(user, item, user_emb,
                                                             itemT, out, B);
    } else {
        gather_dot_direct<<<(B + 255) / 256, 256, 0, stream>>>(user, item, user_emb,
                                                               item_emb, out, B, N);
    }
}